// Round 2
// baseline (1447.702 us; speedup 1.0000x reference)
//
#include <hip/hip_runtime.h>
#include <stdint.h>

static constexpr int N_NODES = 200000;
static constexpr int N_EDGES = 6400000;
static constexpr int F_INC = 128;
static constexpr int F1 = 12;
static constexpr int F2 = 24;
static constexpr int NB_SCAN = (N_NODES + 1023) / 1024; // 196

__device__ __forceinline__ int clampN(int v) {
    // defensive: keep indices in-range so a bad cast can't fault
    return min(max(v, 0), N_NODES - 1);
}

__global__ void zero_int(int* __restrict__ p, int n) {
    int i = blockIdx.x * blockDim.x + threadIdx.x;
    if (i < n) p[i] = 0;
}

__global__ void count_deg(const int* __restrict__ col, int* __restrict__ cnt) {
    int e = blockIdx.x * blockDim.x + threadIdx.x;
    if (e < N_EDGES) atomicAdd(&cnt[clampN(col[e])], 1);
}

// Per-block inclusive scan of 1024 counts; writes block-local exclusive prefix
// to offs, block total to bsum, and dinv = rsqrt(deg+1).
__global__ __launch_bounds__(1024) void scan1(const int* __restrict__ cnt,
                                              int* __restrict__ offs,
                                              int* __restrict__ bsum,
                                              float* __restrict__ dinv) {
    __shared__ int tmp[1024];
    int t = threadIdx.x;
    int i = blockIdx.x * 1024 + t;
    int v = (i < N_NODES) ? cnt[i] : 0;
    if (i < N_NODES) dinv[i] = rsqrtf((float)(v + 1));
    tmp[t] = v;
    for (int off = 1; off < 1024; off <<= 1) {
        __syncthreads();
        int a = (t >= off) ? tmp[t - off] : 0;
        __syncthreads();
        tmp[t] += a;
    }
    __syncthreads();
    if (i < N_NODES) offs[i] = tmp[t] - v;
    if (t == 1023) bsum[blockIdx.x] = tmp[1023];
}

__global__ __launch_bounds__(256) void scan2(int* __restrict__ bsum, int nb) {
    __shared__ int tmp[256];
    int t = threadIdx.x;
    int v = (t < nb) ? bsum[t] : 0;
    tmp[t] = v;
    for (int off = 1; off < 256; off <<= 1) {
        __syncthreads();
        int a = (t >= off) ? tmp[t - off] : 0;
        __syncthreads();
        tmp[t] += a;
    }
    __syncthreads();
    if (t < nb) bsum[t] = tmp[t] - v; // exclusive
}

__global__ void scan3(int* __restrict__ offs, const int* __restrict__ bsum,
                      int* __restrict__ cursor) {
    int i = blockIdx.x * blockDim.x + threadIdx.x;
    if (i < N_NODES) {
        int o = offs[i] + bsum[i >> 10];
        offs[i] = o;
        cursor[i] = o;
    }
    if (i == 0) offs[N_NODES] = N_EDGES;
}

__global__ void fill_csr(const int* __restrict__ row,
                         const int* __restrict__ col,
                         int* __restrict__ cursor, int* __restrict__ csr) {
    int e = blockIdx.x * blockDim.x + threadIdx.x;
    if (e < N_EDGES) {
        int c = clampN(col[e]);
        int p = atomicAdd(&cursor[c], 1);
        if (p >= 0 && p < N_EDGES) csr[p] = clampN(row[e]);
    }
}

// hs1[v] = (x[v] @ W1) * dinv[v]
__global__ __launch_bounds__(256) void gemm1(const float* __restrict__ x,
                                             const float* __restrict__ W1,
                                             const float* __restrict__ dinv,
                                             float* __restrict__ hs1) {
    __shared__ float Wl[F_INC * F1]; // 1536 floats = 6 KB
    for (int i = threadIdx.x; i < F_INC * F1; i += 256) Wl[i] = W1[i];
    __syncthreads();
    int v = blockIdx.x * 256 + threadIdx.x;
    if (v >= N_NODES) return;
    float acc[F1];
#pragma unroll
    for (int f = 0; f < F1; f++) acc[f] = 0.f;
    const float4* xr = (const float4*)(x + (size_t)v * F_INC);
    for (int k4 = 0; k4 < F_INC / 4; k4++) {
        float4 xv = xr[k4];
        int kb = k4 * 4;
#pragma unroll
        for (int f = 0; f < F1; f++) {
            acc[f] += xv.x * Wl[(kb + 0) * F1 + f] + xv.y * Wl[(kb + 1) * F1 + f] +
                      xv.z * Wl[(kb + 2) * F1 + f] + xv.w * Wl[(kb + 3) * F1 + f];
        }
    }
    float dv = dinv[v];
    float4* o = (float4*)(hs1 + (size_t)v * F1);
    float4 r0, r1, r2;
    r0.x = acc[0] * dv;  r0.y = acc[1] * dv;  r0.z = acc[2] * dv;  r0.w = acc[3] * dv;
    r1.x = acc[4] * dv;  r1.y = acc[5] * dv;  r1.z = acc[6] * dv;  r1.w = acc[7] * dv;
    r2.x = acc[8] * dv;  r2.y = acc[9] * dv;  r2.z = acc[10] * dv; r2.w = acc[11] * dv;
    o[0] = r0; o[1] = r1; o[2] = r2;
}

// Layer-1 aggregate + relu + layer-2 feature transform: hs2 = dinv * (relu(out1) @ W2)
__global__ __launch_bounds__(256) void agg1_gemm2(const float* __restrict__ hs1,
                                                  const int* __restrict__ offs,
                                                  const int* __restrict__ csr,
                                                  const float* __restrict__ dinv,
                                                  const float* __restrict__ W2,
                                                  const float* __restrict__ b1,
                                                  float* __restrict__ hs2) {
    __shared__ float Wl[F1 * F2]; // 288 floats
    __shared__ float bl[F1];
    for (int i = threadIdx.x; i < F1 * F2; i += 256) Wl[i] = W2[i];
    if (threadIdx.x < F1) bl[threadIdx.x] = b1[threadIdx.x];
    __syncthreads();
    int v = blockIdx.x * 256 + threadIdx.x;
    if (v >= N_NODES) return;
    float acc[F1];
    {
        const float4* p = (const float4*)(hs1 + (size_t)v * F1);
#pragma unroll
        for (int j = 0; j < 3; j++) {
            float4 t = p[j];
            acc[4 * j + 0] = t.x; acc[4 * j + 1] = t.y;
            acc[4 * j + 2] = t.z; acc[4 * j + 3] = t.w;
        }
    }
    int s = offs[v], e = offs[v + 1];
    for (int i = s; i < e; i++) {
        int idx = csr[i];
        const float4* q = (const float4*)(hs1 + (size_t)idx * F1);
#pragma unroll
        for (int j = 0; j < 3; j++) {
            float4 t = q[j];
            acc[4 * j + 0] += t.x; acc[4 * j + 1] += t.y;
            acc[4 * j + 2] += t.z; acc[4 * j + 3] += t.w;
        }
    }
    float dv = dinv[v];
    float o[F1];
#pragma unroll
    for (int f = 0; f < F1; f++) o[f] = fmaxf(dv * acc[f] + bl[f], 0.f);
    float h2[F2];
#pragma unroll
    for (int g = 0; g < F2; g++) {
        float sum = 0.f;
#pragma unroll
        for (int f = 0; f < F1; f++) sum += o[f] * Wl[f * F2 + g];
        h2[g] = dv * sum;
    }
    float4* op = (float4*)(hs2 + (size_t)v * F2);
#pragma unroll
    for (int j = 0; j < 6; j++) {
        float4 t;
        t.x = h2[4 * j + 0]; t.y = h2[4 * j + 1];
        t.z = h2[4 * j + 2]; t.w = h2[4 * j + 3];
        op[j] = t;
    }
}

// Layer-2 aggregate + relu + fc1(relu) + fc2 -> logits [N,2]
__global__ __launch_bounds__(256) void agg2_fc(const float* __restrict__ hs2,
                                               const int* __restrict__ offs,
                                               const int* __restrict__ csr,
                                               const float* __restrict__ dinv,
                                               const float* __restrict__ b2,
                                               const float* __restrict__ Wf1,
                                               const float* __restrict__ bf1,
                                               const float* __restrict__ Wf2,
                                               const float* __restrict__ bf2,
                                               float* __restrict__ out) {
    __shared__ float W1s[F2 * 32]; // 768
    __shared__ float W2s[32 * 2];  // 64
    __shared__ float b2s[F2], b1s[32], bfs[2];
    for (int i = threadIdx.x; i < F2 * 32; i += 256) W1s[i] = Wf1[i];
    if (threadIdx.x < 64) W2s[threadIdx.x] = Wf2[threadIdx.x];
    if (threadIdx.x < F2) b2s[threadIdx.x] = b2[threadIdx.x];
    if (threadIdx.x < 32) b1s[threadIdx.x] = bf1[threadIdx.x];
    if (threadIdx.x < 2) bfs[threadIdx.x] = bf2[threadIdx.x];
    __syncthreads();
    int v = blockIdx.x * 256 + threadIdx.x;
    if (v >= N_NODES) return;
    float acc[F2];
    {
        const float4* p = (const float4*)(hs2 + (size_t)v * F2);
#pragma unroll
        for (int j = 0; j < 6; j++) {
            float4 t = p[j];
            acc[4 * j + 0] = t.x; acc[4 * j + 1] = t.y;
            acc[4 * j + 2] = t.z; acc[4 * j + 3] = t.w;
        }
    }
    int s = offs[v], e = offs[v + 1];
    for (int i = s; i < e; i++) {
        int idx = csr[i];
        const float4* q = (const float4*)(hs2 + (size_t)idx * F2);
#pragma unroll
        for (int j = 0; j < 6; j++) {
            float4 t = q[j];
            acc[4 * j + 0] += t.x; acc[4 * j + 1] += t.y;
            acc[4 * j + 2] += t.z; acc[4 * j + 3] += t.w;
        }
    }
    float dv = dinv[v];
    float o2[F2];
#pragma unroll
    for (int f = 0; f < F2; f++) o2[f] = fmaxf(dv * acc[f] + b2s[f], 0.f);
    float c0 = bfs[0], c1 = bfs[1];
#pragma unroll
    for (int g = 0; g < 32; g++) {
        float sum = b1s[g];
#pragma unroll
        for (int f = 0; f < F2; f++) sum += o2[f] * W1s[f * 32 + g];
        sum = fmaxf(sum, 0.f);
        c0 += sum * W2s[2 * g + 0];
        c1 += sum * W2s[2 * g + 1];
    }
    float2 r; r.x = c0; r.y = c1;
    ((float2*)out)[v] = r;
}

extern "C" void kernel_launch(void* const* d_in, const int* in_sizes, int n_in,
                              void* d_out, int out_size, void* d_ws, size_t ws_size,
                              hipStream_t stream) {
    const float* x = (const float*)d_in[0];
    // edge_index is delivered as int32 (harness converts integer inputs to int)
    const int* erow = (const int*)d_in[1];
    const int* ecol = erow + N_EDGES;
    const float* W1 = (const float*)d_in[2];
    const float* b1 = (const float*)d_in[3];
    const float* W2 = (const float*)d_in[4];
    const float* b2 = (const float*)d_in[5];
    const float* Wf1 = (const float*)d_in[6];
    const float* bf1 = (const float*)d_in[7];
    const float* Wf2 = (const float*)d_in[8];
    const float* bf2 = (const float*)d_in[9];
    float* out = (float*)d_out;

    char* w = (char*)d_ws;
    auto alloc = [&](size_t bytes) -> char* {
        char* p = w;
        w += (bytes + 255) / 256 * 256;
        return p;
    };
    // cnt buffer is reused as cursor (cnt dead after scan1)
    int* cnt = (int*)alloc((size_t)N_NODES * 4);
    int* cursor = cnt;
    int* offs = (int*)alloc((size_t)(N_NODES + 1) * 4);
    int* bsum = (int*)alloc(1024);
    float* dinv = (float*)alloc((size_t)N_NODES * 4);
    float* hs1 = (float*)alloc((size_t)N_NODES * F1 * 4);
    float* hs2 = (float*)alloc((size_t)N_NODES * F2 * 4);
    int* csr = (int*)alloc((size_t)N_EDGES * 4);

    const int nodeGrid = (N_NODES + 255) / 256;
    const int edgeGrid = (N_EDGES + 255) / 256;

    hipLaunchKernelGGL(zero_int, dim3(nodeGrid), dim3(256), 0, stream, cnt, N_NODES);
    hipLaunchKernelGGL(count_deg, dim3(edgeGrid), dim3(256), 0, stream, ecol, cnt);
    hipLaunchKernelGGL(scan1, dim3(NB_SCAN), dim3(1024), 0, stream, cnt, offs, bsum, dinv);
    hipLaunchKernelGGL(scan2, dim3(1), dim3(256), 0, stream, bsum, NB_SCAN);
    hipLaunchKernelGGL(scan3, dim3(nodeGrid), dim3(256), 0, stream, offs, bsum, cursor);
    hipLaunchKernelGGL(fill_csr, dim3(edgeGrid), dim3(256), 0, stream, erow, ecol, cursor, csr);
    hipLaunchKernelGGL(gemm1, dim3(nodeGrid), dim3(256), 0, stream, x, W1, dinv, hs1);
    hipLaunchKernelGGL(agg1_gemm2, dim3(nodeGrid), dim3(256), 0, stream,
                       hs1, offs, csr, dinv, W2, b1, hs2);
    hipLaunchKernelGGL(agg2_fc, dim3(nodeGrid), dim3(256), 0, stream,
                       hs2, offs, csr, dinv, b2, Wf1, bf1, Wf2, bf2, out);
}

// Round 3
// 939.359 us; speedup vs baseline: 1.5412x; 1.5412x over previous
//
#include <hip/hip_runtime.h>
#include <stdint.h>

static constexpr int N_NODES = 200000;
static constexpr int N_EDGES = 6400000;
static constexpr int F_INC = 128;
static constexpr int F1 = 12;
static constexpr int F2 = 24;
static constexpr int NBUCK = (N_NODES + 255) / 256; // 782 buckets of 256 dest nodes
static constexpr int A1_CHUNK = 4096;
static constexpr int A2_CHUNK = 16384;

__device__ __forceinline__ int clampN(int v) {
    return min(max(v, 0), N_NODES - 1);
}

// ---- zero bucket counters ----
__global__ __launch_bounds__(1024) void zero_bcnt(int* __restrict__ bcnt) {
    int i = threadIdx.x;
    if (i < NBUCK) bcnt[i] = 0;
}

// ---- pass A1: bucket histogram (dest >> 8) ----
__global__ __launch_bounds__(256) void bucket_count(const int* __restrict__ col,
                                                    int* __restrict__ bcnt) {
    __shared__ int h[NBUCK];
    for (int i = threadIdx.x; i < NBUCK; i += 256) h[i] = 0;
    __syncthreads();
    int base = blockIdx.x * A1_CHUNK;
#pragma unroll
    for (int it = 0; it < A1_CHUNK / 256; it++) {
        int e = base + it * 256 + threadIdx.x;
        if (e < N_EDGES) atomicAdd(&h[clampN(col[e]) >> 8], 1);
    }
    __syncthreads();
    for (int i = threadIdx.x; i < NBUCK; i += 256)
        if (h[i]) atomicAdd(&bcnt[i], h[i]);
}

// ---- pass S: scan bucket counts -> bbase (NBUCK+1), init bcur ----
__global__ __launch_bounds__(1024) void bucket_scan(const int* __restrict__ bcnt,
                                                    int* __restrict__ bbase,
                                                    int* __restrict__ bcur,
                                                    int* __restrict__ offs) {
    __shared__ int tmp[1024];
    int t = threadIdx.x;
    int v = (t < NBUCK) ? bcnt[t] : 0;
    tmp[t] = v;
    for (int off = 1; off < 1024; off <<= 1) {
        __syncthreads();
        int a = (t >= off) ? tmp[t - off] : 0;
        __syncthreads();
        tmp[t] += a;
    }
    __syncthreads();
    if (t < NBUCK) {
        int excl = tmp[t] - v;
        bbase[t] = excl;
        bcur[t] = excl;
    }
    if (t == 0) {
        bbase[NBUCK] = N_EDGES;
        offs[N_NODES] = N_EDGES;
    }
}

// ---- pass A2: scatter packed (row<<8 | col&255) into bucket-grouped tmp ----
__global__ __launch_bounds__(256) void bucket_scatter(const int* __restrict__ row,
                                                      const int* __restrict__ col,
                                                      int* __restrict__ bcur,
                                                      int* __restrict__ tmpArr) {
    __shared__ int h[NBUCK];
    __shared__ int curb[NBUCK];
    for (int i = threadIdx.x; i < NBUCK; i += 256) h[i] = 0;
    __syncthreads();
    int base = blockIdx.x * A2_CHUNK;
#pragma unroll 4
    for (int it = 0; it < A2_CHUNK / 256; it++) {
        int e = base + it * 256 + threadIdx.x;
        if (e < N_EDGES) atomicAdd(&h[clampN(col[e]) >> 8], 1);
    }
    __syncthreads();
    for (int i = threadIdx.x; i < NBUCK; i += 256) {
        int c = h[i];
        curb[i] = c ? atomicAdd(&bcur[i], c) : 0;
    }
    __syncthreads();
#pragma unroll 4
    for (int it = 0; it < A2_CHUNK / 256; it++) {
        int e = base + it * 256 + threadIdx.x;
        if (e < N_EDGES) {
            int c = clampN(col[e]);
            int r = clampN(row[e]);
            int b = c >> 8;
            int p = atomicAdd(&curb[b], 1);
            tmpArr[p] = (r << 8) | (c & 255);
        }
    }
}

// ---- pass C: per-bucket degree hist -> offs/dinv (coalesced) + CSR fill via LDS cursors ----
__global__ __launch_bounds__(256) void bucket_fill(const int* __restrict__ tmpArr,
                                                   const int* __restrict__ bbase,
                                                   int* __restrict__ offs,
                                                   float* __restrict__ dinv,
                                                   int* __restrict__ csr) {
    __shared__ int h[256];
    __shared__ int sc[256];
    int b = blockIdx.x;
    int t = threadIdx.x;
    int node0 = b << 8;
    int nn = min(256, N_NODES - node0);
    int s = bbase[b], e = bbase[b + 1];
    h[t] = 0;
    __syncthreads();
    for (int i = s + t; i < e; i += 256) atomicAdd(&h[tmpArr[i] & 255], 1);
    __syncthreads();
    int deg = h[t];
    sc[t] = deg;
    for (int off = 1; off < 256; off <<= 1) {
        __syncthreads();
        int a = (t >= off) ? sc[t - off] : 0;
        __syncthreads();
        sc[t] += a;
    }
    __syncthreads();
    int excl = sc[t] - deg;
    if (t < nn) {
        offs[node0 + t] = s + excl;
        dinv[node0 + t] = rsqrtf((float)(deg + 1));
    }
    h[t] = s + excl; // reuse as cursor
    __syncthreads();
    for (int i = s + t; i < e; i += 256) {
        int en = tmpArr[i];
        int p = atomicAdd(&h[en & 255], 1);
        csr[p] = en >> 8;
    }
}

// ---- hs1[v] = (x[v] @ W1) * dinv[v] ----
__global__ __launch_bounds__(256) void gemm1(const float* __restrict__ x,
                                             const float* __restrict__ W1,
                                             const float* __restrict__ dinv,
                                             float* __restrict__ hs1) {
    __shared__ float Wl[F_INC * F1];
    for (int i = threadIdx.x; i < F_INC * F1; i += 256) Wl[i] = W1[i];
    __syncthreads();
    int v = blockIdx.x * 256 + threadIdx.x;
    if (v >= N_NODES) return;
    float acc[F1];
#pragma unroll
    for (int f = 0; f < F1; f++) acc[f] = 0.f;
    const float4* xr = (const float4*)(x + (size_t)v * F_INC);
    for (int k4 = 0; k4 < F_INC / 4; k4++) {
        float4 xv = xr[k4];
        int kb = k4 * 4;
#pragma unroll
        for (int f = 0; f < F1; f++) {
            acc[f] += xv.x * Wl[(kb + 0) * F1 + f] + xv.y * Wl[(kb + 1) * F1 + f] +
                      xv.z * Wl[(kb + 2) * F1 + f] + xv.w * Wl[(kb + 3) * F1 + f];
        }
    }
    float dv = dinv[v];
    float4* o = (float4*)(hs1 + (size_t)v * F1);
    float4 r0, r1, r2;
    r0.x = acc[0] * dv;  r0.y = acc[1] * dv;  r0.z = acc[2] * dv;  r0.w = acc[3] * dv;
    r1.x = acc[4] * dv;  r1.y = acc[5] * dv;  r1.z = acc[6] * dv;  r1.w = acc[7] * dv;
    r2.x = acc[8] * dv;  r2.y = acc[9] * dv;  r2.z = acc[10] * dv; r2.w = acc[11] * dv;
    o[0] = r0; o[1] = r1; o[2] = r2;
}

// ---- layer-1 aggregate + relu + layer-2 transform ----
__global__ __launch_bounds__(256) void agg1_gemm2(const float* __restrict__ hs1,
                                                  const int* __restrict__ offs,
                                                  const int* __restrict__ csr,
                                                  const float* __restrict__ dinv,
                                                  const float* __restrict__ W2,
                                                  const float* __restrict__ b1,
                                                  float* __restrict__ hs2) {
    __shared__ float Wl[F1 * F2];
    __shared__ float bl[F1];
    for (int i = threadIdx.x; i < F1 * F2; i += 256) Wl[i] = W2[i];
    if (threadIdx.x < F1) bl[threadIdx.x] = b1[threadIdx.x];
    __syncthreads();
    int v = blockIdx.x * 256 + threadIdx.x;
    if (v >= N_NODES) return;
    float acc[F1];
    {
        const float4* p = (const float4*)(hs1 + (size_t)v * F1);
#pragma unroll
        for (int j = 0; j < 3; j++) {
            float4 t = p[j];
            acc[4 * j + 0] = t.x; acc[4 * j + 1] = t.y;
            acc[4 * j + 2] = t.z; acc[4 * j + 3] = t.w;
        }
    }
    int s = offs[v], e = offs[v + 1];
    for (int i = s; i < e; i++) {
        int idx = csr[i];
        const float4* q = (const float4*)(hs1 + (size_t)idx * F1);
#pragma unroll
        for (int j = 0; j < 3; j++) {
            float4 t = q[j];
            acc[4 * j + 0] += t.x; acc[4 * j + 1] += t.y;
            acc[4 * j + 2] += t.z; acc[4 * j + 3] += t.w;
        }
    }
    float dv = dinv[v];
    float o[F1];
#pragma unroll
    for (int f = 0; f < F1; f++) o[f] = fmaxf(dv * acc[f] + bl[f], 0.f);
    float h2[F2];
#pragma unroll
    for (int g = 0; g < F2; g++) {
        float sum = 0.f;
#pragma unroll
        for (int f = 0; f < F1; f++) sum += o[f] * Wl[f * F2 + g];
        h2[g] = dv * sum;
    }
    float4* op = (float4*)(hs2 + (size_t)v * F2);
#pragma unroll
    for (int j = 0; j < 6; j++) {
        float4 t;
        t.x = h2[4 * j + 0]; t.y = h2[4 * j + 1];
        t.z = h2[4 * j + 2]; t.w = h2[4 * j + 3];
        op[j] = t;
    }
}

// ---- layer-2 aggregate + relu + fc1(relu) + fc2 -> logits ----
__global__ __launch_bounds__(256) void agg2_fc(const float* __restrict__ hs2,
                                               const int* __restrict__ offs,
                                               const int* __restrict__ csr,
                                               const float* __restrict__ dinv,
                                               const float* __restrict__ b2,
                                               const float* __restrict__ Wf1,
                                               const float* __restrict__ bf1,
                                               const float* __restrict__ Wf2,
                                               const float* __restrict__ bf2,
                                               float* __restrict__ out) {
    __shared__ float W1s[F2 * 32];
    __shared__ float W2s[32 * 2];
    __shared__ float b2s[F2], b1s[32], bfs[2];
    for (int i = threadIdx.x; i < F2 * 32; i += 256) W1s[i] = Wf1[i];
    if (threadIdx.x < 64) W2s[threadIdx.x] = Wf2[threadIdx.x];
    if (threadIdx.x < F2) b2s[threadIdx.x] = b2[threadIdx.x];
    if (threadIdx.x < 32) b1s[threadIdx.x] = bf1[threadIdx.x];
    if (threadIdx.x < 2) bfs[threadIdx.x] = bf2[threadIdx.x];
    __syncthreads();
    int v = blockIdx.x * 256 + threadIdx.x;
    if (v >= N_NODES) return;
    float acc[F2];
    {
        const float4* p = (const float4*)(hs2 + (size_t)v * F2);
#pragma unroll
        for (int j = 0; j < 6; j++) {
            float4 t = p[j];
            acc[4 * j + 0] = t.x; acc[4 * j + 1] = t.y;
            acc[4 * j + 2] = t.z; acc[4 * j + 3] = t.w;
        }
    }
    int s = offs[v], e = offs[v + 1];
    for (int i = s; i < e; i++) {
        int idx = csr[i];
        const float4* q = (const float4*)(hs2 + (size_t)idx * F2);
#pragma unroll
        for (int j = 0; j < 6; j++) {
            float4 t = q[j];
            acc[4 * j + 0] += t.x; acc[4 * j + 1] += t.y;
            acc[4 * j + 2] += t.z; acc[4 * j + 3] += t.w;
        }
    }
    float dv = dinv[v];
    float o2[F2];
#pragma unroll
    for (int f = 0; f < F2; f++) o2[f] = fmaxf(dv * acc[f] + b2s[f], 0.f);
    float c0 = bfs[0], c1 = bfs[1];
#pragma unroll
    for (int g = 0; g < 32; g++) {
        float sum = b1s[g];
#pragma unroll
        for (int f = 0; f < F2; f++) sum += o2[f] * W1s[f * 32 + g];
        sum = fmaxf(sum, 0.f);
        c0 += sum * W2s[2 * g + 0];
        c1 += sum * W2s[2 * g + 1];
    }
    float2 r; r.x = c0; r.y = c1;
    ((float2*)out)[v] = r;
}

extern "C" void kernel_launch(void* const* d_in, const int* in_sizes, int n_in,
                              void* d_out, int out_size, void* d_ws, size_t ws_size,
                              hipStream_t stream) {
    const float* x = (const float*)d_in[0];
    const int* erow = (const int*)d_in[1]; // edge_index delivered as int32
    const int* ecol = erow + N_EDGES;
    const float* W1 = (const float*)d_in[2];
    const float* b1 = (const float*)d_in[3];
    const float* W2 = (const float*)d_in[4];
    const float* b2 = (const float*)d_in[5];
    const float* Wf1 = (const float*)d_in[6];
    const float* bf1 = (const float*)d_in[7];
    const float* Wf2 = (const float*)d_in[8];
    const float* bf2 = (const float*)d_in[9];
    float* out = (float*)d_out;

    char* w = (char*)d_ws;
    auto alloc = [&](size_t bytes) -> char* {
        char* p = w;
        w += (bytes + 255) / 256 * 256;
        return p;
    };
    int* bcnt = (int*)alloc((size_t)NBUCK * 4);
    int* bbase = (int*)alloc((size_t)(NBUCK + 1) * 4);
    int* bcur = (int*)alloc((size_t)NBUCK * 4);
    int* offs = (int*)alloc((size_t)(N_NODES + 1) * 4);
    float* dinv = (float*)alloc((size_t)N_NODES * 4);
    int* csr = (int*)alloc((size_t)N_EDGES * 4);
    // union region: tmpArr (E ints) dies before hs1/hs2 are written
    char* uni = alloc((size_t)N_NODES * (F1 + F2) * 4); // 28.8 MB >= 25.6 MB
    int* tmpArr = (int*)uni;
    float* hs1 = (float*)uni;
    float* hs2 = (float*)(uni + (size_t)N_NODES * F1 * 4);

    const int nodeGrid = (N_NODES + 255) / 256;
    const int a1Grid = (N_EDGES + A1_CHUNK - 1) / A1_CHUNK;  // 1563
    const int a2Grid = (N_EDGES + A2_CHUNK - 1) / A2_CHUNK;  // 391

    hipLaunchKernelGGL(zero_bcnt, dim3(1), dim3(1024), 0, stream, bcnt);
    hipLaunchKernelGGL(bucket_count, dim3(a1Grid), dim3(256), 0, stream, ecol, bcnt);
    hipLaunchKernelGGL(bucket_scan, dim3(1), dim3(1024), 0, stream, bcnt, bbase, bcur, offs);
    hipLaunchKernelGGL(bucket_scatter, dim3(a2Grid), dim3(256), 0, stream, erow, ecol, bcur, tmpArr);
    hipLaunchKernelGGL(bucket_fill, dim3(NBUCK), dim3(256), 0, stream, tmpArr, bbase, offs, dinv, csr);
    hipLaunchKernelGGL(gemm1, dim3(nodeGrid), dim3(256), 0, stream, x, W1, dinv, hs1);
    hipLaunchKernelGGL(agg1_gemm2, dim3(nodeGrid), dim3(256), 0, stream,
                       hs1, offs, csr, dinv, W2, b1, hs2);
    hipLaunchKernelGGL(agg2_fc, dim3(nodeGrid), dim3(256), 0, stream,
                       hs2, offs, csr, dinv, b2, Wf1, bf1, Wf2, bf2, out);
}

// Round 4
// 729.444 us; speedup vs baseline: 1.9847x; 1.2878x over previous
//
#include <hip/hip_runtime.h>
#include <hip/hip_fp16.h>
#include <stdint.h>

static constexpr int N_NODES = 200000;
static constexpr int N_EDGES = 6400000;
static constexpr int F_INC = 128;
static constexpr int F1 = 12;
static constexpr int F2 = 24;
static constexpr int HS1_STRIDE = 16; // floats (64 B line)
static constexpr int HS2_STRIDE = 32; // halfs  (64 B line)
static constexpr int NBUCK = (N_NODES + 255) / 256; // 782
static constexpr int A1_CHUNK = 4096;
static constexpr int A2_CHUNK = 16384;

__device__ __forceinline__ int clampN(int v) {
    return min(max(v, 0), N_NODES - 1);
}

// ---- zero bucket counters ----
__global__ __launch_bounds__(1024) void zero_bcnt(int* __restrict__ bcnt) {
    int i = threadIdx.x;
    if (i < NBUCK) bcnt[i] = 0;
}

// ---- pass A1: bucket histogram (dest >> 8) ----
__global__ __launch_bounds__(256) void bucket_count(const int* __restrict__ col,
                                                    int* __restrict__ bcnt) {
    __shared__ int h[NBUCK];
    for (int i = threadIdx.x; i < NBUCK; i += 256) h[i] = 0;
    __syncthreads();
    int base = blockIdx.x * A1_CHUNK;
#pragma unroll
    for (int it = 0; it < A1_CHUNK / 256; it++) {
        int e = base + it * 256 + threadIdx.x;
        if (e < N_EDGES) atomicAdd(&h[clampN(col[e]) >> 8], 1);
    }
    __syncthreads();
    for (int i = threadIdx.x; i < NBUCK; i += 256)
        if (h[i]) atomicAdd(&bcnt[i], h[i]);
}

// ---- pass S: scan bucket counts -> bbase (NBUCK+1), init bcur ----
__global__ __launch_bounds__(1024) void bucket_scan(const int* __restrict__ bcnt,
                                                    int* __restrict__ bbase,
                                                    int* __restrict__ bcur,
                                                    int* __restrict__ offs) {
    __shared__ int tmp[1024];
    int t = threadIdx.x;
    int v = (t < NBUCK) ? bcnt[t] : 0;
    tmp[t] = v;
    for (int off = 1; off < 1024; off <<= 1) {
        __syncthreads();
        int a = (t >= off) ? tmp[t - off] : 0;
        __syncthreads();
        tmp[t] += a;
    }
    __syncthreads();
    if (t < NBUCK) {
        int excl = tmp[t] - v;
        bbase[t] = excl;
        bcur[t] = excl;
    }
    if (t == 0) {
        bbase[NBUCK] = N_EDGES;
        offs[N_NODES] = N_EDGES;
    }
}

// ---- pass A2: scatter packed (row<<8 | col&255) into bucket-grouped tmp ----
__global__ __launch_bounds__(256) void bucket_scatter(const int* __restrict__ row,
                                                      const int* __restrict__ col,
                                                      int* __restrict__ bcur,
                                                      int* __restrict__ tmpArr) {
    __shared__ int h[NBUCK];
    __shared__ int curb[NBUCK];
    for (int i = threadIdx.x; i < NBUCK; i += 256) h[i] = 0;
    __syncthreads();
    int base = blockIdx.x * A2_CHUNK;
#pragma unroll 4
    for (int it = 0; it < A2_CHUNK / 256; it++) {
        int e = base + it * 256 + threadIdx.x;
        if (e < N_EDGES) atomicAdd(&h[clampN(col[e]) >> 8], 1);
    }
    __syncthreads();
    for (int i = threadIdx.x; i < NBUCK; i += 256) {
        int c = h[i];
        curb[i] = c ? atomicAdd(&bcur[i], c) : 0;
    }
    __syncthreads();
#pragma unroll 4
    for (int it = 0; it < A2_CHUNK / 256; it++) {
        int e = base + it * 256 + threadIdx.x;
        if (e < N_EDGES) {
            int c = clampN(col[e]);
            int r = clampN(row[e]);
            int b = c >> 8;
            int p = atomicAdd(&curb[b], 1);
            tmpArr[p] = (r << 8) | (c & 255);
        }
    }
}

// ---- pass C: per-bucket degree hist -> offs/dinv + CSR fill via LDS cursors ----
__global__ __launch_bounds__(256) void bucket_fill(const int* __restrict__ tmpArr,
                                                   const int* __restrict__ bbase,
                                                   int* __restrict__ offs,
                                                   float* __restrict__ dinv,
                                                   int* __restrict__ csr) {
    __shared__ int h[256];
    __shared__ int sc[256];
    int b = blockIdx.x;
    int t = threadIdx.x;
    int node0 = b << 8;
    int nn = min(256, N_NODES - node0);
    int s = bbase[b], e = bbase[b + 1];
    h[t] = 0;
    __syncthreads();
    for (int i = s + t; i < e; i += 256) atomicAdd(&h[tmpArr[i] & 255], 1);
    __syncthreads();
    int deg = h[t];
    sc[t] = deg;
    for (int off = 1; off < 256; off <<= 1) {
        __syncthreads();
        int a = (t >= off) ? sc[t - off] : 0;
        __syncthreads();
        sc[t] += a;
    }
    __syncthreads();
    int excl = sc[t] - deg;
    if (t < nn) {
        offs[node0 + t] = s + excl;
        dinv[node0 + t] = rsqrtf((float)(deg + 1));
    }
    h[t] = s + excl; // reuse as cursor
    __syncthreads();
    for (int i = s + t; i < e; i += 256) {
        int en = tmpArr[i];
        int p = atomicAdd(&h[en & 255], 1);
        csr[p] = en >> 8;
    }
}

// ---- hs1[v*16 .. +12] = (x[v] @ W1) * dinv[v], 64B-aligned rows ----
__global__ __launch_bounds__(256) void gemm1(const float* __restrict__ x,
                                             const float* __restrict__ W1,
                                             const float* __restrict__ dinv,
                                             float* __restrict__ hs1) {
    __shared__ float Wl[F_INC * F1];
    for (int i = threadIdx.x; i < F_INC * F1; i += 256) Wl[i] = W1[i];
    __syncthreads();
    int v = blockIdx.x * 256 + threadIdx.x;
    if (v >= N_NODES) return;
    float acc[F1];
#pragma unroll
    for (int f = 0; f < F1; f++) acc[f] = 0.f;
    const float4* xr = (const float4*)(x + (size_t)v * F_INC);
    for (int k4 = 0; k4 < F_INC / 4; k4++) {
        float4 xv = xr[k4];
        int kb = k4 * 4;
#pragma unroll
        for (int f = 0; f < F1; f++) {
            acc[f] += xv.x * Wl[(kb + 0) * F1 + f] + xv.y * Wl[(kb + 1) * F1 + f] +
                      xv.z * Wl[(kb + 2) * F1 + f] + xv.w * Wl[(kb + 3) * F1 + f];
        }
    }
    float dv = dinv[v];
    float4* o = (float4*)(hs1 + (size_t)v * HS1_STRIDE);
    float4 r0, r1, r2;
    r0.x = acc[0] * dv;  r0.y = acc[1] * dv;  r0.z = acc[2] * dv;  r0.w = acc[3] * dv;
    r1.x = acc[4] * dv;  r1.y = acc[5] * dv;  r1.z = acc[6] * dv;  r1.w = acc[7] * dv;
    r2.x = acc[8] * dv;  r2.y = acc[9] * dv;  r2.z = acc[10] * dv; r2.w = acc[11] * dv;
    o[0] = r0; o[1] = r1; o[2] = r2;
}

__device__ __forceinline__ void add_row1(float* acc, const float4* q) {
    float4 t0 = q[0], t1 = q[1], t2 = q[2];
    acc[0] += t0.x; acc[1] += t0.y; acc[2]  += t0.z; acc[3]  += t0.w;
    acc[4] += t1.x; acc[5] += t1.y; acc[6]  += t1.z; acc[7]  += t1.w;
    acc[8] += t2.x; acc[9] += t2.y; acc[10] += t2.z; acc[11] += t2.w;
}

// ---- layer-1 aggregate + relu + layer-2 transform -> hs2 (fp16) ----
__global__ __launch_bounds__(256) void agg1_gemm2(const float* __restrict__ hs1,
                                                  const int* __restrict__ offs,
                                                  const int* __restrict__ csr,
                                                  const float* __restrict__ dinv,
                                                  const float* __restrict__ W2,
                                                  const float* __restrict__ b1,
                                                  __half* __restrict__ hs2) {
    __shared__ float Wl[F1 * F2];
    __shared__ float bl[F1];
    for (int i = threadIdx.x; i < F1 * F2; i += 256) Wl[i] = W2[i];
    if (threadIdx.x < F1) bl[threadIdx.x] = b1[threadIdx.x];
    __syncthreads();
    int v = blockIdx.x * 256 + threadIdx.x;
    if (v >= N_NODES) return;
    float acc[F1];
#pragma unroll
    for (int f = 0; f < F1; f++) acc[f] = 0.f;
    add_row1(acc, (const float4*)(hs1 + (size_t)v * HS1_STRIDE));
    int s = offs[v], e = offs[v + 1];
    int i = s;
    for (; i + 4 <= e; i += 4) {
        int i0 = csr[i], i1 = csr[i + 1], i2 = csr[i + 2], i3 = csr[i + 3];
        const float4* q0 = (const float4*)(hs1 + (size_t)i0 * HS1_STRIDE);
        const float4* q1 = (const float4*)(hs1 + (size_t)i1 * HS1_STRIDE);
        const float4* q2 = (const float4*)(hs1 + (size_t)i2 * HS1_STRIDE);
        const float4* q3 = (const float4*)(hs1 + (size_t)i3 * HS1_STRIDE);
        add_row1(acc, q0); add_row1(acc, q1); add_row1(acc, q2); add_row1(acc, q3);
    }
    for (; i < e; i++)
        add_row1(acc, (const float4*)(hs1 + (size_t)csr[i] * HS1_STRIDE));
    float dv = dinv[v];
    float o[F1];
#pragma unroll
    for (int f = 0; f < F1; f++) o[f] = fmaxf(dv * acc[f] + bl[f], 0.f);
    float h2[F2];
#pragma unroll
    for (int g = 0; g < F2; g++) {
        float sum = 0.f;
#pragma unroll
        for (int f = 0; f < F1; f++) sum += o[f] * Wl[f * F2 + g];
        h2[g] = dv * sum;
    }
    int w[12];
#pragma unroll
    for (int j = 0; j < 12; j++) {
        __half2 p = __floats2half2_rn(h2[2 * j], h2[2 * j + 1]);
        w[j] = *(int*)&p;
    }
    int4* op = (int4*)(hs2 + (size_t)v * HS2_STRIDE);
    op[0] = make_int4(w[0], w[1], w[2], w[3]);
    op[1] = make_int4(w[4], w[5], w[6], w[7]);
    op[2] = make_int4(w[8], w[9], w[10], w[11]);
}

__device__ __forceinline__ void add_row2(float* acc, const int4* q) {
    int4 a = q[0], b = q[1], c = q[2];
    int ws[12] = {a.x, a.y, a.z, a.w, b.x, b.y, b.z, b.w, c.x, c.y, c.z, c.w};
#pragma unroll
    for (int j = 0; j < 12; j++) {
        __half2 h = *(__half2*)&ws[j];
        float2 f = __half22float2(h);
        acc[2 * j] += f.x;
        acc[2 * j + 1] += f.y;
    }
}

// ---- layer-2 aggregate + relu + fc1(relu) + fc2 -> logits ----
__global__ __launch_bounds__(256) void agg2_fc(const __half* __restrict__ hs2,
                                               const int* __restrict__ offs,
                                               const int* __restrict__ csr,
                                               const float* __restrict__ dinv,
                                               const float* __restrict__ b2,
                                               const float* __restrict__ Wf1,
                                               const float* __restrict__ bf1,
                                               const float* __restrict__ Wf2,
                                               const float* __restrict__ bf2,
                                               float* __restrict__ out) {
    __shared__ float W1s[F2 * 32];
    __shared__ float W2s[32 * 2];
    __shared__ float b2s[F2], b1s[32], bfs[2];
    for (int i = threadIdx.x; i < F2 * 32; i += 256) W1s[i] = Wf1[i];
    if (threadIdx.x < 64) W2s[threadIdx.x] = Wf2[threadIdx.x];
    if (threadIdx.x < F2) b2s[threadIdx.x] = b2[threadIdx.x];
    if (threadIdx.x < 32) b1s[threadIdx.x] = bf1[threadIdx.x];
    if (threadIdx.x < 2) bfs[threadIdx.x] = bf2[threadIdx.x];
    __syncthreads();
    int v = blockIdx.x * 256 + threadIdx.x;
    if (v >= N_NODES) return;
    float acc[F2];
#pragma unroll
    for (int f = 0; f < F2; f++) acc[f] = 0.f;
    add_row2(acc, (const int4*)(hs2 + (size_t)v * HS2_STRIDE));
    int s = offs[v], e = offs[v + 1];
    int i = s;
    for (; i + 4 <= e; i += 4) {
        int i0 = csr[i], i1 = csr[i + 1], i2 = csr[i + 2], i3 = csr[i + 3];
        const int4* q0 = (const int4*)(hs2 + (size_t)i0 * HS2_STRIDE);
        const int4* q1 = (const int4*)(hs2 + (size_t)i1 * HS2_STRIDE);
        const int4* q2 = (const int4*)(hs2 + (size_t)i2 * HS2_STRIDE);
        const int4* q3 = (const int4*)(hs2 + (size_t)i3 * HS2_STRIDE);
        add_row2(acc, q0); add_row2(acc, q1); add_row2(acc, q2); add_row2(acc, q3);
    }
    for (; i < e; i++)
        add_row2(acc, (const int4*)(hs2 + (size_t)csr[i] * HS2_STRIDE));
    float dv = dinv[v];
    float o2[F2];
#pragma unroll
    for (int f = 0; f < F2; f++) o2[f] = fmaxf(dv * acc[f] + b2s[f], 0.f);
    float c0 = bfs[0], c1 = bfs[1];
#pragma unroll
    for (int g = 0; g < 32; g++) {
        float sum = b1s[g];
#pragma unroll
        for (int f = 0; f < F2; f++) sum += o2[f] * W1s[f * 32 + g];
        sum = fmaxf(sum, 0.f);
        c0 += sum * W2s[2 * g + 0];
        c1 += sum * W2s[2 * g + 1];
    }
    float2 r; r.x = c0; r.y = c1;
    ((float2*)out)[v] = r;
}

extern "C" void kernel_launch(void* const* d_in, const int* in_sizes, int n_in,
                              void* d_out, int out_size, void* d_ws, size_t ws_size,
                              hipStream_t stream) {
    const float* x = (const float*)d_in[0];
    const int* erow = (const int*)d_in[1]; // edge_index delivered as int32
    const int* ecol = erow + N_EDGES;
    const float* W1 = (const float*)d_in[2];
    const float* b1 = (const float*)d_in[3];
    const float* W2 = (const float*)d_in[4];
    const float* b2 = (const float*)d_in[5];
    const float* Wf1 = (const float*)d_in[6];
    const float* bf1 = (const float*)d_in[7];
    const float* Wf2 = (const float*)d_in[8];
    const float* bf2 = (const float*)d_in[9];
    float* out = (float*)d_out;

    char* w = (char*)d_ws;
    auto alloc = [&](size_t bytes) -> char* {
        char* p = w;
        w += (bytes + 255) / 256 * 256;
        return p;
    };
    int* bcnt = (int*)alloc((size_t)NBUCK * 4);
    int* bbase = (int*)alloc((size_t)(NBUCK + 1) * 4);
    int* bcur = (int*)alloc((size_t)NBUCK * 4);
    int* offs = (int*)alloc((size_t)(N_NODES + 1) * 4);
    float* dinv = (float*)alloc((size_t)N_NODES * 4);
    int* csr = (int*)alloc((size_t)N_EDGES * 4);
    // union region: tmpArr (E ints = 25.6 MB) dies before hs1/hs2 are written
    size_t hs1_bytes = (size_t)N_NODES * HS1_STRIDE * 4; // 12.8 MB
    size_t hs2_bytes = (size_t)N_NODES * HS2_STRIDE * 2; // 12.8 MB
    size_t uni_bytes = hs1_bytes + hs2_bytes;            // 25.6 MB >= tmp
    char* uni = alloc(uni_bytes);
    int* tmpArr = (int*)uni;
    float* hs1 = (float*)uni;
    __half* hs2 = (__half*)(uni + hs1_bytes);

    const int nodeGrid = (N_NODES + 255) / 256;
    const int a1Grid = (N_EDGES + A1_CHUNK - 1) / A1_CHUNK;
    const int a2Grid = (N_EDGES + A2_CHUNK - 1) / A2_CHUNK;

    hipLaunchKernelGGL(zero_bcnt, dim3(1), dim3(1024), 0, stream, bcnt);
    hipLaunchKernelGGL(bucket_count, dim3(a1Grid), dim3(256), 0, stream, ecol, bcnt);
    hipLaunchKernelGGL(bucket_scan, dim3(1), dim3(1024), 0, stream, bcnt, bbase, bcur, offs);
    hipLaunchKernelGGL(bucket_scatter, dim3(a2Grid), dim3(256), 0, stream, erow, ecol, bcur, tmpArr);
    hipLaunchKernelGGL(bucket_fill, dim3(NBUCK), dim3(256), 0, stream, tmpArr, bbase, offs, dinv, csr);
    hipLaunchKernelGGL(gemm1, dim3(nodeGrid), dim3(256), 0, stream, x, W1, dinv, hs1);
    hipLaunchKernelGGL(agg1_gemm2, dim3(nodeGrid), dim3(256), 0, stream,
                       hs1, offs, csr, dinv, W2, b1, hs2);
    hipLaunchKernelGGL(agg2_fc, dim3(nodeGrid), dim3(256), 0, stream,
                       hs2, offs, csr, dinv, b2, Wf1, bf1, Wf2, bf2, out);
}